// Round 1
// baseline (3056.040 us; speedup 1.0000x reference)
//
#include <hip/hip_runtime.h>

#define EMB     128
#define NUSERS  80000
#define NITEMS  40000
#define NNODES  120000
#define NNZV    600000
#define BATCHN  4096

// ---------------- SpMM layer 1: gather from virtual concat(user_emb, item_emb)
__global__ __launch_bounds__(256) void spmm_first(
    const int* __restrict__ row, const int* __restrict__ col,
    const float* __restrict__ val,
    const float* __restrict__ ue, const float* __restrict__ ie,
    float* __restrict__ out)
{
    int e = blockIdx.x * 8 + (threadIdx.x >> 5);
    if (e >= NNZV) return;
    int lane = threadIdx.x & 31;
    int r = row[e];
    int c = col[e];
    float v = val[e];
    const float4* src = (c < NUSERS)
        ? ((const float4*)ue) + (size_t)c * 32
        : ((const float4*)ie) + (size_t)(c - NUSERS) * 32;
    float4 x = src[lane];
    float* dst = out + (size_t)r * EMB + lane * 4;
    unsafeAtomicAdd(dst + 0, v * x.x);
    unsafeAtomicAdd(dst + 1, v * x.y);
    unsafeAtomicAdd(dst + 2, v * x.z);
    unsafeAtomicAdd(dst + 3, v * x.w);
}

// ---------------- SpMM layers 2..: gather from previous h
__global__ __launch_bounds__(256) void spmm_next(
    const int* __restrict__ row, const int* __restrict__ col,
    const float* __restrict__ val,
    const float* __restrict__ hin, float* __restrict__ out)
{
    int e = blockIdx.x * 8 + (threadIdx.x >> 5);
    if (e >= NNZV) return;
    int lane = threadIdx.x & 31;
    int r = row[e];
    int c = col[e];
    float v = val[e];
    float4 x = ((const float4*)hin)[(size_t)c * 32 + lane];
    float* dst = out + (size_t)r * EMB + lane * 4;
    unsafeAtomicAdd(dst + 0, v * x.x);
    unsafeAtomicAdd(dst + 1, v * x.y);
    unsafeAtomicAdd(dst + 2, v * x.z);
    unsafeAtomicAdd(dst + 3, v * x.w);
}

// ---------------- full item slab: i_g = (ie + h1 + h2 + h3)/4
__global__ __launch_bounds__(256) void finalize_items(
    const float* __restrict__ ie,
    const float* __restrict__ h1, const float* __restrict__ h2,
    const float* __restrict__ h3, float* __restrict__ out)
{
    int i = blockIdx.x * blockDim.x + threadIdx.x;  // float4 index
    if (i >= NITEMS * EMB / 4) return;
    float4 a = ((const float4*)ie)[i];
    size_t off = (size_t)NUSERS * 32 + i;
    float4 b = ((const float4*)h1)[off];
    float4 c = ((const float4*)h2)[off];
    float4 d = ((const float4*)h3)[off];
    float4 r;
    r.x = (a.x + b.x + c.x + d.x) * 0.25f;
    r.y = (a.y + b.y + c.y + d.y) * 0.25f;
    r.z = (a.z + b.z + c.z + d.z) * 0.25f;
    r.w = (a.w + b.w + c.w + d.w) * 0.25f;
    ((float4*)out)[i] = r;
}

// ---------------- batched gathers: out[b] = (emb0[idx] + h1[base+idx] + ...)/4
__global__ __launch_bounds__(256) void finalize_gather(
    const int* __restrict__ idx, int base,
    const float* __restrict__ emb0,
    const float* __restrict__ h1, const float* __restrict__ h2,
    const float* __restrict__ h3, float* __restrict__ out)
{
    int b = blockIdx.x * 8 + (threadIdx.x >> 5);
    if (b >= BATCHN) return;
    int lane = threadIdx.x & 31;
    int r = idx[b];
    float4 a = ((const float4*)emb0)[(size_t)r * 32 + lane];
    size_t off = (size_t)(base + r) * 32 + lane;
    float4 x1 = ((const float4*)h1)[off];
    float4 x2 = ((const float4*)h2)[off];
    float4 x3 = ((const float4*)h3)[off];
    float4 o;
    o.x = (a.x + x1.x + x2.x + x3.x) * 0.25f;
    o.y = (a.y + x1.y + x2.y + x3.y) * 0.25f;
    o.z = (a.z + x1.z + x2.z + x3.z) * 0.25f;
    o.w = (a.w + x1.w + x2.w + x3.w) * 0.25f;
    ((float4*)out)[(size_t)b * 32 + lane] = o;
}

extern "C" void kernel_launch(void* const* d_in, const int* in_sizes, int n_in,
                              void* d_out, int out_size, void* d_ws, size_t ws_size,
                              hipStream_t stream)
{
    const int*   users = (const int*)d_in[0];
    const int*   pos   = (const int*)d_in[1];
    const int*   neg   = (const int*)d_in[2];
    const float* ue    = (const float*)d_in[3];
    const float* ie    = (const float*)d_in[4];
    const int*   arow  = (const int*)d_in[5];
    const int*   acol  = (const int*)d_in[6];
    const float* aval  = (const float*)d_in[7];
    // d_in[8] = n_layers (fixed at 3 per problem constants)

    const size_t hElems = (size_t)NNODES * EMB;
    float* h1 = (float*)d_ws;
    float* h2 = h1 + hElems;
    float* h3 = h2 + hElems;

    hipMemsetAsync(h1, 0, hElems * 3 * sizeof(float), stream);

    int eblocks = (NNZV + 7) / 8;
    spmm_first<<<eblocks, 256, 0, stream>>>(arow, acol, aval, ue, ie, h1);
    spmm_next <<<eblocks, 256, 0, stream>>>(arow, acol, aval, h1, h2);
    spmm_next <<<eblocks, 256, 0, stream>>>(arow, acol, aval, h2, h3);

    float* out = (float*)d_out;
    float* u_g = out;
    float* p_g = u_g + (size_t)BATCHN * EMB;
    float* n_g = p_g + (size_t)BATCHN * EMB;
    float* i_g = n_g + (size_t)BATCHN * EMB;

    int gblocks = (BATCHN + 7) / 8;
    finalize_gather<<<gblocks, 256, 0, stream>>>(users, 0,      ue, h1, h2, h3, u_g);
    finalize_gather<<<gblocks, 256, 0, stream>>>(pos,   NUSERS, ie, h1, h2, h3, p_g);
    finalize_gather<<<gblocks, 256, 0, stream>>>(neg,   NUSERS, ie, h1, h2, h3, n_g);

    int iblocks = (NITEMS * EMB / 4 + 255) / 256;
    finalize_items<<<iblocks, 256, 0, stream>>>(ie, h1, h2, h3, i_g);
}

// Round 2
// 282.241 us; speedup vs baseline: 10.8278x; 10.8278x over previous
//
#include <hip/hip_runtime.h>

#define EMB     128
#define NUSERS  80000
#define NITEMS  40000
#define NNODES  120000
#define NNZV    600000
#define BATCHN  4096

#define SCAN_BLK   1024
#define SCAN_GRID  ((NNODES + SCAN_BLK - 1) / SCAN_BLK)   // 118

// ---------------- CSR build: histogram of rows
__global__ __launch_bounds__(256) void count_rows(
    const int* __restrict__ row, int* __restrict__ counts)
{
    int e = blockIdx.x * 256 + threadIdx.x;
    if (e >= NNZV) return;
    atomicAdd(&counts[row[e]], 1);
}

// ---------------- block-level exclusive scan; excl goes into `start`
__global__ __launch_bounds__(SCAN_BLK) void scan_block(
    const int* __restrict__ counts, int* __restrict__ start,
    int* __restrict__ partials)
{
    __shared__ int lds[SCAN_BLK];
    int tid = threadIdx.x;
    int gid = blockIdx.x * SCAN_BLK + tid;
    int v = (gid < NNODES) ? counts[gid] : 0;
    lds[tid] = v;
    __syncthreads();
    for (int off = 1; off < SCAN_BLK; off <<= 1) {
        int t = (tid >= off) ? lds[tid - off] : 0;
        __syncthreads();
        lds[tid] += t;
        __syncthreads();
    }
    if (gid < NNODES) start[gid] = lds[tid] - v;       // exclusive within block
    if (tid == SCAN_BLK - 1) partials[blockIdx.x] = lds[tid];  // block total
}

// ---------------- scan the 118 block totals (single block, in place -> exclusive)
__global__ __launch_bounds__(128) void scan_partials(int* __restrict__ partials)
{
    __shared__ int lds[128];
    int tid = threadIdx.x;
    int v = (tid < SCAN_GRID) ? partials[tid] : 0;
    lds[tid] = v;
    __syncthreads();
    for (int off = 1; off < 128; off <<= 1) {
        int t = (tid >= off) ? lds[tid - off] : 0;
        __syncthreads();
        lds[tid] += t;
        __syncthreads();
    }
    if (tid < SCAN_GRID) partials[tid] = lds[tid] - v; // exclusive
}

// ---------------- add block offsets
__global__ __launch_bounds__(SCAN_BLK) void add_offsets(
    int* __restrict__ start, const int* __restrict__ partials)
{
    int gid = blockIdx.x * SCAN_BLK + threadIdx.x;
    if (gid < NNODES) start[gid] += partials[blockIdx.x];
}

// ---------------- scatter edges into row-sorted order
__global__ __launch_bounds__(256) void scatter_edges(
    const int* __restrict__ row, const int* __restrict__ col,
    const float* __restrict__ val,
    const int* __restrict__ start, int* __restrict__ cursor,
    int* __restrict__ scol, float* __restrict__ sval)
{
    int e = blockIdx.x * 256 + threadIdx.x;
    if (e >= NNZV) return;
    int r = row[e];
    int p = atomicAdd(&cursor[r], 1);
    int d = start[r] + p;
    scol[d] = col[e];
    sval[d] = val[e];
}

// ---------------- pull SpMM, layer 1 (virtual concat source)
__global__ __launch_bounds__(256) void spmm_pull_first(
    const int* __restrict__ start, const int* __restrict__ counts,
    const int* __restrict__ scol, const float* __restrict__ sval,
    const float* __restrict__ ue, const float* __restrict__ ie,
    float* __restrict__ out)
{
    int r = blockIdx.x * 8 + (threadIdx.x >> 5);
    if (r >= NNODES) return;
    int lane = threadIdx.x & 31;
    int s = start[r], n = counts[r];
    float4 acc = {0.f, 0.f, 0.f, 0.f};
    for (int j = 0; j < n; ++j) {
        int c = scol[s + j];
        float v = sval[s + j];
        const float4* src = (c < NUSERS)
            ? ((const float4*)ue) + (size_t)c * 32
            : ((const float4*)ie) + (size_t)(c - NUSERS) * 32;
        float4 x = src[lane];
        acc.x += v * x.x; acc.y += v * x.y;
        acc.z += v * x.z; acc.w += v * x.w;
    }
    ((float4*)out)[(size_t)r * 32 + lane] = acc;
}

// ---------------- pull SpMM, layers 2..
__global__ __launch_bounds__(256) void spmm_pull(
    const int* __restrict__ start, const int* __restrict__ counts,
    const int* __restrict__ scol, const float* __restrict__ sval,
    const float* __restrict__ hin, float* __restrict__ out)
{
    int r = blockIdx.x * 8 + (threadIdx.x >> 5);
    if (r >= NNODES) return;
    int lane = threadIdx.x & 31;
    int s = start[r], n = counts[r];
    float4 acc = {0.f, 0.f, 0.f, 0.f};
    for (int j = 0; j < n; ++j) {
        int c = scol[s + j];
        float v = sval[s + j];
        float4 x = ((const float4*)hin)[(size_t)c * 32 + lane];
        acc.x += v * x.x; acc.y += v * x.y;
        acc.z += v * x.z; acc.w += v * x.w;
    }
    ((float4*)out)[(size_t)r * 32 + lane] = acc;
}

// ---------------- full item slab: i_g = (ie + h1 + h2 + h3)/4
__global__ __launch_bounds__(256) void finalize_items(
    const float* __restrict__ ie,
    const float* __restrict__ h1, const float* __restrict__ h2,
    const float* __restrict__ h3, float* __restrict__ out)
{
    int i = blockIdx.x * blockDim.x + threadIdx.x;  // float4 index
    if (i >= NITEMS * EMB / 4) return;
    float4 a = ((const float4*)ie)[i];
    size_t off = (size_t)NUSERS * 32 + i;
    float4 b = ((const float4*)h1)[off];
    float4 c = ((const float4*)h2)[off];
    float4 d = ((const float4*)h3)[off];
    float4 r;
    r.x = (a.x + b.x + c.x + d.x) * 0.25f;
    r.y = (a.y + b.y + c.y + d.y) * 0.25f;
    r.z = (a.z + b.z + c.z + d.z) * 0.25f;
    r.w = (a.w + b.w + c.w + d.w) * 0.25f;
    ((float4*)out)[i] = r;
}

// ---------------- batched gathers
__global__ __launch_bounds__(256) void finalize_gather(
    const int* __restrict__ idx, int base,
    const float* __restrict__ emb0,
    const float* __restrict__ h1, const float* __restrict__ h2,
    const float* __restrict__ h3, float* __restrict__ out)
{
    int b = blockIdx.x * 8 + (threadIdx.x >> 5);
    if (b >= BATCHN) return;
    int lane = threadIdx.x & 31;
    int r = idx[b];
    float4 a = ((const float4*)emb0)[(size_t)r * 32 + lane];
    size_t off = (size_t)(base + r) * 32 + lane;
    float4 x1 = ((const float4*)h1)[off];
    float4 x2 = ((const float4*)h2)[off];
    float4 x3 = ((const float4*)h3)[off];
    float4 o;
    o.x = (a.x + x1.x + x2.x + x3.x) * 0.25f;
    o.y = (a.y + x1.y + x2.y + x3.y) * 0.25f;
    o.z = (a.z + x1.z + x2.z + x3.z) * 0.25f;
    o.w = (a.w + x1.w + x2.w + x3.w) * 0.25f;
    ((float4*)out)[(size_t)b * 32 + lane] = o;
}

extern "C" void kernel_launch(void* const* d_in, const int* in_sizes, int n_in,
                              void* d_out, int out_size, void* d_ws, size_t ws_size,
                              hipStream_t stream)
{
    const int*   users = (const int*)d_in[0];
    const int*   pos   = (const int*)d_in[1];
    const int*   neg   = (const int*)d_in[2];
    const float* ue    = (const float*)d_in[3];
    const float* ie    = (const float*)d_in[4];
    const int*   arow  = (const int*)d_in[5];
    const int*   acol  = (const int*)d_in[6];
    const float* aval  = (const float*)d_in[7];

    const size_t hElems = (size_t)NNODES * EMB;
    char* ws = (char*)d_ws;
    float* h1      = (float*)ws;                       ws += hElems * sizeof(float);
    float* h2      = (float*)ws;                       ws += hElems * sizeof(float);
    float* h3      = (float*)ws;                       ws += hElems * sizeof(float);
    int*   counts  = (int*)ws;                         ws += NNODES * sizeof(int);
    int*   startp  = (int*)ws;                         ws += NNODES * sizeof(int);
    int*   cursor  = (int*)ws;                         ws += NNODES * sizeof(int);
    int*   partials= (int*)ws;                         ws += 128 * sizeof(int);
    int*   scol    = (int*)ws;                         ws += NNZV * sizeof(int);
    float* sval    = (float*)ws;                       ws += NNZV * sizeof(float);

    // zero histogram + cursors (960 KB)
    hipMemsetAsync(counts, 0, NNODES * sizeof(int), stream);
    hipMemsetAsync(cursor, 0, NNODES * sizeof(int), stream);

    // ---- CSR build
    int eblk256 = (NNZV + 255) / 256;
    count_rows   <<<eblk256, 256, 0, stream>>>(arow, counts);
    scan_block   <<<SCAN_GRID, SCAN_BLK, 0, stream>>>(counts, startp, partials);
    scan_partials<<<1, 128, 0, stream>>>(partials);
    add_offsets  <<<SCAN_GRID, SCAN_BLK, 0, stream>>>(startp, partials);
    scatter_edges<<<eblk256, 256, 0, stream>>>(arow, acol, aval, startp, cursor, scol, sval);

    // ---- 3 pull-SpMM layers
    int rblocks = (NNODES + 7) / 8;
    spmm_pull_first<<<rblocks, 256, 0, stream>>>(startp, counts, scol, sval, ue, ie, h1);
    spmm_pull      <<<rblocks, 256, 0, stream>>>(startp, counts, scol, sval, h1, h2);
    spmm_pull      <<<rblocks, 256, 0, stream>>>(startp, counts, scol, sval, h2, h3);

    // ---- outputs
    float* out = (float*)d_out;
    float* u_g = out;
    float* p_g = u_g + (size_t)BATCHN * EMB;
    float* n_g = p_g + (size_t)BATCHN * EMB;
    float* i_g = n_g + (size_t)BATCHN * EMB;

    int gblocks = (BATCHN + 7) / 8;
    finalize_gather<<<gblocks, 256, 0, stream>>>(users, 0,      ue, h1, h2, h3, u_g);
    finalize_gather<<<gblocks, 256, 0, stream>>>(pos,   NUSERS, ie, h1, h2, h3, p_g);
    finalize_gather<<<gblocks, 256, 0, stream>>>(neg,   NUSERS, ie, h1, h2, h3, n_g);

    int iblocks = (NITEMS * EMB / 4 + 255) / 256;
    finalize_items<<<iblocks, 256, 0, stream>>>(ie, h1, h2, h3, i_g);
}

// Round 3
// 234.667 us; speedup vs baseline: 13.0229x; 1.2027x over previous
//
#include <hip/hip_runtime.h>

#define EMB     128
#define NUSERS  80000
#define NITEMS  40000
#define NNODES  120000
#define NNZV    600000
#define BATCHN  4096

#define SCAN_BLK   1024
#define SCAN_GRID  ((NNODES + SCAN_BLK - 1) / SCAN_BLK)   // 118

// ---------------- CSR build pass 1: histogram + per-edge slot
__global__ __launch_bounds__(256) void count_rows(
    const int* __restrict__ row, int* __restrict__ counts,
    int* __restrict__ slot)
{
    int e = blockIdx.x * 256 + threadIdx.x;
    if (e >= NNZV) return;
    slot[e] = atomicAdd(&counts[row[e]], 1);
}

// ---------------- block-level exclusive scan; excl goes into `start`
__global__ __launch_bounds__(SCAN_BLK) void scan_block(
    const int* __restrict__ counts, int* __restrict__ start,
    int* __restrict__ partials)
{
    __shared__ int lds[SCAN_BLK];
    int tid = threadIdx.x;
    int gid = blockIdx.x * SCAN_BLK + tid;
    int v = (gid < NNODES) ? counts[gid] : 0;
    lds[tid] = v;
    __syncthreads();
    for (int off = 1; off < SCAN_BLK; off <<= 1) {
        int t = (tid >= off) ? lds[tid - off] : 0;
        __syncthreads();
        lds[tid] += t;
        __syncthreads();
    }
    if (gid < NNODES) start[gid] = lds[tid] - v;
    if (tid == SCAN_BLK - 1) partials[blockIdx.x] = lds[tid];
}

__global__ __launch_bounds__(128) void scan_partials(int* __restrict__ partials)
{
    __shared__ int lds[128];
    int tid = threadIdx.x;
    int v = (tid < SCAN_GRID) ? partials[tid] : 0;
    lds[tid] = v;
    __syncthreads();
    for (int off = 1; off < 128; off <<= 1) {
        int t = (tid >= off) ? lds[tid - off] : 0;
        __syncthreads();
        lds[tid] += t;
        __syncthreads();
    }
    if (tid < SCAN_GRID) partials[tid] = lds[tid] - v;
}

__global__ __launch_bounds__(SCAN_BLK) void add_offsets(
    int* __restrict__ start, const int* __restrict__ partials)
{
    int gid = blockIdx.x * SCAN_BLK + threadIdx.x;
    if (gid < NNODES) start[gid] += partials[blockIdx.x];
}

// ---------------- CSR build pass 2: place packed edges {col, val}
__global__ __launch_bounds__(256) void scatter_edges(
    const int* __restrict__ row, const int* __restrict__ col,
    const float* __restrict__ val,
    const int* __restrict__ start, const int* __restrict__ slot,
    int2* __restrict__ edges)
{
    int e = blockIdx.x * 256 + threadIdx.x;
    if (e >= NNZV) return;
    int d = start[row[e]] + slot[e];
    edges[d] = make_int2(col[e], __float_as_int(val[e]));
}

// ---------------- pull SpMM, layer 1 (virtual concat source), 4-wide MLP
__global__ __launch_bounds__(256) void spmm_pull_first(
    const int* __restrict__ start, const int* __restrict__ counts,
    const int2* __restrict__ edges,
    const float* __restrict__ ue, const float* __restrict__ ie,
    float* __restrict__ out)
{
    int r = blockIdx.x * 8 + (threadIdx.x >> 5);
    if (r >= NNODES) return;
    int lane = threadIdx.x & 31;
    int n = counts[r];
    const int2* e = edges + start[r];
    float4 acc = {0.f, 0.f, 0.f, 0.f};
    int j = 0;
    for (; j + 4 <= n; j += 4) {
        int2 e0 = e[j], e1 = e[j+1], e2 = e[j+2], e3 = e[j+3];
        const float4* s0 = (e0.x < NUSERS) ? ((const float4*)ue) + (size_t)e0.x * 32
                                           : ((const float4*)ie) + (size_t)(e0.x - NUSERS) * 32;
        const float4* s1 = (e1.x < NUSERS) ? ((const float4*)ue) + (size_t)e1.x * 32
                                           : ((const float4*)ie) + (size_t)(e1.x - NUSERS) * 32;
        const float4* s2 = (e2.x < NUSERS) ? ((const float4*)ue) + (size_t)e2.x * 32
                                           : ((const float4*)ie) + (size_t)(e2.x - NUSERS) * 32;
        const float4* s3 = (e3.x < NUSERS) ? ((const float4*)ue) + (size_t)e3.x * 32
                                           : ((const float4*)ie) + (size_t)(e3.x - NUSERS) * 32;
        float4 x0 = s0[lane], x1 = s1[lane], x2 = s2[lane], x3 = s3[lane];
        float v0 = __int_as_float(e0.y), v1 = __int_as_float(e1.y);
        float v2 = __int_as_float(e2.y), v3 = __int_as_float(e3.y);
        acc.x += v0*x0.x + v1*x1.x + v2*x2.x + v3*x3.x;
        acc.y += v0*x0.y + v1*x1.y + v2*x2.y + v3*x3.y;
        acc.z += v0*x0.z + v1*x1.z + v2*x2.z + v3*x3.z;
        acc.w += v0*x0.w + v1*x1.w + v2*x2.w + v3*x3.w;
    }
    for (; j < n; ++j) {
        int2 ej = e[j];
        const float4* sj = (ej.x < NUSERS) ? ((const float4*)ue) + (size_t)ej.x * 32
                                           : ((const float4*)ie) + (size_t)(ej.x - NUSERS) * 32;
        float4 x = sj[lane];
        float v = __int_as_float(ej.y);
        acc.x += v*x.x; acc.y += v*x.y; acc.z += v*x.z; acc.w += v*x.w;
    }
    ((float4*)out)[(size_t)r * 32 + lane] = acc;
}

// ---------------- pull SpMM, layers 2.., 4-wide MLP
__global__ __launch_bounds__(256) void spmm_pull(
    const int* __restrict__ start, const int* __restrict__ counts,
    const int2* __restrict__ edges,
    const float* __restrict__ hin, float* __restrict__ out)
{
    int r = blockIdx.x * 8 + (threadIdx.x >> 5);
    if (r >= NNODES) return;
    int lane = threadIdx.x & 31;
    int n = counts[r];
    const int2* e = edges + start[r];
    const float4* H = (const float4*)hin;
    float4 acc = {0.f, 0.f, 0.f, 0.f};
    int j = 0;
    for (; j + 4 <= n; j += 4) {
        int2 e0 = e[j], e1 = e[j+1], e2 = e[j+2], e3 = e[j+3];
        float4 x0 = H[(size_t)e0.x * 32 + lane];
        float4 x1 = H[(size_t)e1.x * 32 + lane];
        float4 x2 = H[(size_t)e2.x * 32 + lane];
        float4 x3 = H[(size_t)e3.x * 32 + lane];
        float v0 = __int_as_float(e0.y), v1 = __int_as_float(e1.y);
        float v2 = __int_as_float(e2.y), v3 = __int_as_float(e3.y);
        acc.x += v0*x0.x + v1*x1.x + v2*x2.x + v3*x3.x;
        acc.y += v0*x0.y + v1*x1.y + v2*x2.y + v3*x3.y;
        acc.z += v0*x0.z + v1*x1.z + v2*x2.z + v3*x3.z;
        acc.w += v0*x0.w + v1*x1.w + v2*x2.w + v3*x3.w;
    }
    for (; j < n; ++j) {
        int2 ej = e[j];
        float4 x = H[(size_t)ej.x * 32 + lane];
        float v = __int_as_float(ej.y);
        acc.x += v*x.x; acc.y += v*x.y; acc.z += v*x.z; acc.w += v*x.w;
    }
    ((float4*)out)[(size_t)r * 32 + lane] = acc;
}

// ---------------- full item slab: i_g = (ie + h1 + h2 + h3)/4
__global__ __launch_bounds__(256) void finalize_items(
    const float* __restrict__ ie,
    const float* __restrict__ h1, const float* __restrict__ h2,
    const float* __restrict__ h3, float* __restrict__ out)
{
    int i = blockIdx.x * blockDim.x + threadIdx.x;
    if (i >= NITEMS * EMB / 4) return;
    float4 a = ((const float4*)ie)[i];
    size_t off = (size_t)NUSERS * 32 + i;
    float4 b = ((const float4*)h1)[off];
    float4 c = ((const float4*)h2)[off];
    float4 d = ((const float4*)h3)[off];
    float4 r;
    r.x = (a.x + b.x + c.x + d.x) * 0.25f;
    r.y = (a.y + b.y + c.y + d.y) * 0.25f;
    r.z = (a.z + b.z + c.z + d.z) * 0.25f;
    r.w = (a.w + b.w + c.w + d.w) * 0.25f;
    ((float4*)out)[i] = r;
}

// ---------------- merged batched gathers: [users | pos | neg] -> out
__global__ __launch_bounds__(256) void finalize_gather3(
    const int* __restrict__ users, const int* __restrict__ pos,
    const int* __restrict__ neg,
    const float* __restrict__ ue, const float* __restrict__ ie,
    const float* __restrict__ h1, const float* __restrict__ h2,
    const float* __restrict__ h3, float* __restrict__ out)
{
    int b = blockIdx.x * 8 + (threadIdx.x >> 5);
    if (b >= 3 * BATCHN) return;
    int lane = threadIdx.x & 31;
    int which = b >> 12;           // BATCHN == 4096
    int bi = b & (BATCHN - 1);
    const int* idx = (which == 0) ? users : (which == 1) ? pos : neg;
    int r = idx[bi];
    const float* emb0 = (which == 0) ? ue : ie;
    int base = (which == 0) ? 0 : NUSERS;
    float4 a = ((const float4*)emb0)[(size_t)r * 32 + lane];
    size_t off = (size_t)(base + r) * 32 + lane;
    float4 x1 = ((const float4*)h1)[off];
    float4 x2 = ((const float4*)h2)[off];
    float4 x3 = ((const float4*)h3)[off];
    float4 o;
    o.x = (a.x + x1.x + x2.x + x3.x) * 0.25f;
    o.y = (a.y + x1.y + x2.y + x3.y) * 0.25f;
    o.z = (a.z + x1.z + x2.z + x3.z) * 0.25f;
    o.w = (a.w + x1.w + x2.w + x3.w) * 0.25f;
    ((float4*)out)[(size_t)b * 32 + lane] = o;
}

extern "C" void kernel_launch(void* const* d_in, const int* in_sizes, int n_in,
                              void* d_out, int out_size, void* d_ws, size_t ws_size,
                              hipStream_t stream)
{
    const int*   users = (const int*)d_in[0];
    const int*   pos   = (const int*)d_in[1];
    const int*   neg   = (const int*)d_in[2];
    const float* ue    = (const float*)d_in[3];
    const float* ie    = (const float*)d_in[4];
    const int*   arow  = (const int*)d_in[5];
    const int*   acol  = (const int*)d_in[6];
    const float* aval  = (const float*)d_in[7];

    const size_t hElems = (size_t)NNODES * EMB;
    char* ws = (char*)d_ws;
    float* h1      = (float*)ws;   ws += hElems * sizeof(float);
    float* h2      = (float*)ws;   ws += hElems * sizeof(float);
    float* h3      = (float*)ws;   ws += hElems * sizeof(float);
    int*   counts  = (int*)ws;     ws += NNODES * sizeof(int);
    int*   startp  = (int*)ws;     ws += NNODES * sizeof(int);
    int*   slot    = (int*)ws;     ws += NNZV * sizeof(int);
    int*   partials= (int*)ws;     ws += 128 * sizeof(int);
    int2*  edges   = (int2*)ws;    ws += NNZV * sizeof(int2);

    hipMemsetAsync(counts, 0, NNODES * sizeof(int), stream);

    // ---- CSR build
    int eblk256 = (NNZV + 255) / 256;
    count_rows   <<<eblk256, 256, 0, stream>>>(arow, counts, slot);
    scan_block   <<<SCAN_GRID, SCAN_BLK, 0, stream>>>(counts, startp, partials);
    scan_partials<<<1, 128, 0, stream>>>(partials);
    add_offsets  <<<SCAN_GRID, SCAN_BLK, 0, stream>>>(startp, partials);
    scatter_edges<<<eblk256, 256, 0, stream>>>(arow, acol, aval, startp, slot, edges);

    // ---- 3 pull-SpMM layers
    int rblocks = (NNODES + 7) / 8;
    spmm_pull_first<<<rblocks, 256, 0, stream>>>(startp, counts, edges, ue, ie, h1);
    spmm_pull      <<<rblocks, 256, 0, stream>>>(startp, counts, edges, h1, h2);
    spmm_pull      <<<rblocks, 256, 0, stream>>>(startp, counts, edges, h2, h3);

    // ---- outputs
    float* out = (float*)d_out;
    float* i_g = out + (size_t)3 * BATCHN * EMB;

    int g3blocks = (3 * BATCHN + 7) / 8;
    finalize_gather3<<<g3blocks, 256, 0, stream>>>(users, pos, neg, ue, ie, h1, h2, h3, out);

    int iblocks = (NITEMS * EMB / 4 + 255) / 256;
    finalize_items<<<iblocks, 256, 0, stream>>>(ie, h1, h2, h3, i_g);
}

// Round 4
// 231.423 us; speedup vs baseline: 13.2055x; 1.0140x over previous
//
#include <hip/hip_runtime.h>

#define EMB     128
#define NUSERS  80000
#define NITEMS  40000
#define NNODES  120000
#define NNZV    600000
#define BATCHN  4096

#define SCAN_BLK   1024
#define SCAN_GRID  ((NNODES + SCAN_BLK - 1) / SCAN_BLK)   // 118

// ---------------- CSR build pass 1: histogram + per-edge slot
__global__ __launch_bounds__(256) void count_rows(
    const int* __restrict__ row, int* __restrict__ counts,
    int* __restrict__ slot)
{
    int e = blockIdx.x * 256 + threadIdx.x;
    if (e >= NNZV) return;
    slot[e] = atomicAdd(&counts[row[e]], 1);
}

// ---------------- block-level exclusive scan; excl goes into `start`
__global__ __launch_bounds__(SCAN_BLK) void scan_block(
    const int* __restrict__ counts, int* __restrict__ start,
    int* __restrict__ partials)
{
    __shared__ int lds[SCAN_BLK];
    int tid = threadIdx.x;
    int gid = blockIdx.x * SCAN_BLK + tid;
    int v = (gid < NNODES) ? counts[gid] : 0;
    lds[tid] = v;
    __syncthreads();
    for (int off = 1; off < SCAN_BLK; off <<= 1) {
        int t = (tid >= off) ? lds[tid - off] : 0;
        __syncthreads();
        lds[tid] += t;
        __syncthreads();
    }
    if (gid < NNODES) start[gid] = lds[tid] - v;
    if (tid == SCAN_BLK - 1) partials[blockIdx.x] = lds[tid];
}

__global__ __launch_bounds__(128) void scan_partials(int* __restrict__ partials)
{
    __shared__ int lds[128];
    int tid = threadIdx.x;
    int v = (tid < SCAN_GRID) ? partials[tid] : 0;
    lds[tid] = v;
    __syncthreads();
    for (int off = 1; off < 128; off <<= 1) {
        int t = (tid >= off) ? lds[tid - off] : 0;
        __syncthreads();
        lds[tid] += t;
        __syncthreads();
    }
    if (tid < SCAN_GRID) partials[tid] = lds[tid] - v;
}

// ---------------- add block offsets + emit packed row descriptors {start,count}
__global__ __launch_bounds__(SCAN_BLK) void add_offsets_desc(
    int* __restrict__ start, const int* __restrict__ partials,
    const int* __restrict__ counts, int2* __restrict__ desc)
{
    int gid = blockIdx.x * SCAN_BLK + threadIdx.x;
    if (gid >= NNODES) return;
    int s = start[gid] + partials[blockIdx.x];
    start[gid] = s;
    desc[gid] = make_int2(s, counts[gid]);
}

// ---------------- CSR build pass 2: place packed edges {col, val}
__global__ __launch_bounds__(256) void scatter_edges(
    const int* __restrict__ row, const int* __restrict__ col,
    const float* __restrict__ val,
    const int* __restrict__ start, const int* __restrict__ slot,
    int2* __restrict__ edges)
{
    int e = blockIdx.x * 256 + threadIdx.x;
    if (e >= NNZV) return;
    int d = start[row[e]] + slot[e];
    edges[d] = make_int2(col[e], __float_as_int(val[e]));
}

// gather helper for virtual concat(ue, ie)
__device__ __forceinline__ const float4* ego_row(
    const float* ue, const float* ie, int c)
{
    return (c < NUSERS) ? ((const float4*)ue) + (size_t)c * 32
                        : ((const float4*)ie) + (size_t)(c - NUSERS) * 32;
}

// ---------------- pull SpMM, layer 1 (virtual concat source), 8-wide head
__global__ __launch_bounds__(256) void spmm_pull_first(
    const int2* __restrict__ desc,
    const int2* __restrict__ edges,
    const float* __restrict__ ue, const float* __restrict__ ie,
    float* __restrict__ out)
{
    int r = blockIdx.x * 8 + (threadIdx.x >> 5);
    if (r >= NNODES) return;
    int lane = threadIdx.x & 31;
    int2 d = desc[r];
    int n = d.y;
    const int2* e = edges + d.x;
    float4 acc = {0.f, 0.f, 0.f, 0.f};
    if (n > 0) {
        int m = n - 1;
        int2 e0 = e[0],        e1 = e[min(1, m)], e2 = e[min(2, m)], e3 = e[min(3, m)];
        int2 e4 = e[min(4, m)], e5 = e[min(5, m)], e6 = e[min(6, m)], e7 = e[min(7, m)];
        float4 x0 = ego_row(ue, ie, e0.x)[lane];
        float4 x1 = ego_row(ue, ie, e1.x)[lane];
        float4 x2 = ego_row(ue, ie, e2.x)[lane];
        float4 x3 = ego_row(ue, ie, e3.x)[lane];
        float4 x4 = ego_row(ue, ie, e4.x)[lane];
        float4 x5 = ego_row(ue, ie, e5.x)[lane];
        float4 x6 = ego_row(ue, ie, e6.x)[lane];
        float4 x7 = ego_row(ue, ie, e7.x)[lane];
        float v0 = __int_as_float(e0.y);
        float v1 = (1 < n) ? __int_as_float(e1.y) : 0.f;
        float v2 = (2 < n) ? __int_as_float(e2.y) : 0.f;
        float v3 = (3 < n) ? __int_as_float(e3.y) : 0.f;
        float v4 = (4 < n) ? __int_as_float(e4.y) : 0.f;
        float v5 = (5 < n) ? __int_as_float(e5.y) : 0.f;
        float v6 = (6 < n) ? __int_as_float(e6.y) : 0.f;
        float v7 = (7 < n) ? __int_as_float(e7.y) : 0.f;
        acc.x = v0*x0.x + v1*x1.x + v2*x2.x + v3*x3.x + v4*x4.x + v5*x5.x + v6*x6.x + v7*x7.x;
        acc.y = v0*x0.y + v1*x1.y + v2*x2.y + v3*x3.y + v4*x4.y + v5*x5.y + v6*x6.y + v7*x7.y;
        acc.z = v0*x0.z + v1*x1.z + v2*x2.z + v3*x3.z + v4*x4.z + v5*x5.z + v6*x6.z + v7*x7.z;
        acc.w = v0*x0.w + v1*x1.w + v2*x2.w + v3*x3.w + v4*x4.w + v5*x5.w + v6*x6.w + v7*x7.w;
        for (int j = 8; j < n; j += 4) {
            int2 a0 = e[min(j,     m)], a1 = e[min(j + 1, m)];
            int2 a2 = e[min(j + 2, m)], a3 = e[min(j + 3, m)];
            float4 y0 = ego_row(ue, ie, a0.x)[lane];
            float4 y1 = ego_row(ue, ie, a1.x)[lane];
            float4 y2 = ego_row(ue, ie, a2.x)[lane];
            float4 y3 = ego_row(ue, ie, a3.x)[lane];
            float w0 = __int_as_float(a0.y);
            float w1 = (j + 1 < n) ? __int_as_float(a1.y) : 0.f;
            float w2 = (j + 2 < n) ? __int_as_float(a2.y) : 0.f;
            float w3 = (j + 3 < n) ? __int_as_float(a3.y) : 0.f;
            acc.x += w0*y0.x + w1*y1.x + w2*y2.x + w3*y3.x;
            acc.y += w0*y0.y + w1*y1.y + w2*y2.y + w3*y3.y;
            acc.z += w0*y0.z + w1*y1.z + w2*y2.z + w3*y3.z;
            acc.w += w0*y0.w + w1*y1.w + w2*y2.w + w3*y3.w;
        }
    }
    ((float4*)out)[(size_t)r * 32 + lane] = acc;
}

// ---------------- pull SpMM, layers 2.., 8-wide head
__global__ __launch_bounds__(256) void spmm_pull(
    const int2* __restrict__ desc,
    const int2* __restrict__ edges,
    const float* __restrict__ hin, float* __restrict__ out)
{
    int r = blockIdx.x * 8 + (threadIdx.x >> 5);
    if (r >= NNODES) return;
    int lane = threadIdx.x & 31;
    int2 d = desc[r];
    int n = d.y;
    const int2* e = edges + d.x;
    const float4* H = (const float4*)hin;
    float4 acc = {0.f, 0.f, 0.f, 0.f};
    if (n > 0) {
        int m = n - 1;
        int2 e0 = e[0],        e1 = e[min(1, m)], e2 = e[min(2, m)], e3 = e[min(3, m)];
        int2 e4 = e[min(4, m)], e5 = e[min(5, m)], e6 = e[min(6, m)], e7 = e[min(7, m)];
        float4 x0 = H[(size_t)e0.x * 32 + lane];
        float4 x1 = H[(size_t)e1.x * 32 + lane];
        float4 x2 = H[(size_t)e2.x * 32 + lane];
        float4 x3 = H[(size_t)e3.x * 32 + lane];
        float4 x4 = H[(size_t)e4.x * 32 + lane];
        float4 x5 = H[(size_t)e5.x * 32 + lane];
        float4 x6 = H[(size_t)e6.x * 32 + lane];
        float4 x7 = H[(size_t)e7.x * 32 + lane];
        float v0 = __int_as_float(e0.y);
        float v1 = (1 < n) ? __int_as_float(e1.y) : 0.f;
        float v2 = (2 < n) ? __int_as_float(e2.y) : 0.f;
        float v3 = (3 < n) ? __int_as_float(e3.y) : 0.f;
        float v4 = (4 < n) ? __int_as_float(e4.y) : 0.f;
        float v5 = (5 < n) ? __int_as_float(e5.y) : 0.f;
        float v6 = (6 < n) ? __int_as_float(e6.y) : 0.f;
        float v7 = (7 < n) ? __int_as_float(e7.y) : 0.f;
        acc.x = v0*x0.x + v1*x1.x + v2*x2.x + v3*x3.x + v4*x4.x + v5*x5.x + v6*x6.x + v7*x7.x;
        acc.y = v0*x0.y + v1*x1.y + v2*x2.y + v3*x3.y + v4*x4.y + v5*x5.y + v6*x6.y + v7*x7.y;
        acc.z = v0*x0.z + v1*x1.z + v2*x2.z + v3*x3.z + v4*x4.z + v5*x5.z + v6*x6.z + v7*x7.z;
        acc.w = v0*x0.w + v1*x1.w + v2*x2.w + v3*x3.w + v4*x4.w + v5*x5.w + v6*x6.w + v7*x7.w;
        for (int j = 8; j < n; j += 4) {
            int2 a0 = e[min(j,     m)], a1 = e[min(j + 1, m)];
            int2 a2 = e[min(j + 2, m)], a3 = e[min(j + 3, m)];
            float4 y0 = H[(size_t)a0.x * 32 + lane];
            float4 y1 = H[(size_t)a1.x * 32 + lane];
            float4 y2 = H[(size_t)a2.x * 32 + lane];
            float4 y3 = H[(size_t)a3.x * 32 + lane];
            float w0 = __int_as_float(a0.y);
            float w1 = (j + 1 < n) ? __int_as_float(a1.y) : 0.f;
            float w2 = (j + 2 < n) ? __int_as_float(a2.y) : 0.f;
            float w3 = (j + 3 < n) ? __int_as_float(a3.y) : 0.f;
            acc.x += w0*y0.x + w1*y1.x + w2*y2.x + w3*y3.x;
            acc.y += w0*y0.y + w1*y1.y + w2*y2.y + w3*y3.y;
            acc.z += w0*y0.z + w1*y1.z + w2*y2.z + w3*y3.z;
            acc.w += w0*y0.w + w1*y1.w + w2*y2.w + w3*y3.w;
        }
    }
    ((float4*)out)[(size_t)r * 32 + lane] = acc;
}

// ---------------- full item slab: i_g = (ie + h1 + h2 + h3)/4
__global__ __launch_bounds__(256) void finalize_items(
    const float* __restrict__ ie,
    const float* __restrict__ h1, const float* __restrict__ h2,
    const float* __restrict__ h3, float* __restrict__ out)
{
    int i = blockIdx.x * blockDim.x + threadIdx.x;
    if (i >= NITEMS * EMB / 4) return;
    float4 a = ((const float4*)ie)[i];
    size_t off = (size_t)NUSERS * 32 + i;
    float4 b = ((const float4*)h1)[off];
    float4 c = ((const float4*)h2)[off];
    float4 d = ((const float4*)h3)[off];
    float4 r;
    r.x = (a.x + b.x + c.x + d.x) * 0.25f;
    r.y = (a.y + b.y + c.y + d.y) * 0.25f;
    r.z = (a.z + b.z + c.z + d.z) * 0.25f;
    r.w = (a.w + b.w + c.w + d.w) * 0.25f;
    ((float4*)out)[i] = r;
}

// ---------------- merged batched gathers: [users | pos | neg] -> out
__global__ __launch_bounds__(256) void finalize_gather3(
    const int* __restrict__ users, const int* __restrict__ pos,
    const int* __restrict__ neg,
    const float* __restrict__ ue, const float* __restrict__ ie,
    const float* __restrict__ h1, const float* __restrict__ h2,
    const float* __restrict__ h3, float* __restrict__ out)
{
    int b = blockIdx.x * 8 + (threadIdx.x >> 5);
    if (b >= 3 * BATCHN) return;
    int lane = threadIdx.x & 31;
    int which = b >> 12;           // BATCHN == 4096
    int bi = b & (BATCHN - 1);
    const int* idx = (which == 0) ? users : (which == 1) ? pos : neg;
    int r = idx[bi];
    const float* emb0 = (which == 0) ? ue : ie;
    int base = (which == 0) ? 0 : NUSERS;
    float4 a = ((const float4*)emb0)[(size_t)r * 32 + lane];
    size_t off = (size_t)(base + r) * 32 + lane;
    float4 x1 = ((const float4*)h1)[off];
    float4 x2 = ((const float4*)h2)[off];
    float4 x3 = ((const float4*)h3)[off];
    float4 o;
    o.x = (a.x + x1.x + x2.x + x3.x) * 0.25f;
    o.y = (a.y + x1.y + x2.y + x3.y) * 0.25f;
    o.z = (a.z + x1.z + x2.z + x3.z) * 0.25f;
    o.w = (a.w + x1.w + x2.w + x3.w) * 0.25f;
    ((float4*)out)[(size_t)b * 32 + lane] = o;
}

extern "C" void kernel_launch(void* const* d_in, const int* in_sizes, int n_in,
                              void* d_out, int out_size, void* d_ws, size_t ws_size,
                              hipStream_t stream)
{
    const int*   users = (const int*)d_in[0];
    const int*   pos   = (const int*)d_in[1];
    const int*   neg   = (const int*)d_in[2];
    const float* ue    = (const float*)d_in[3];
    const float* ie    = (const float*)d_in[4];
    const int*   arow  = (const int*)d_in[5];
    const int*   acol  = (const int*)d_in[6];
    const float* aval  = (const float*)d_in[7];

    const size_t hElems = (size_t)NNODES * EMB;
    char* ws = (char*)d_ws;
    float* h1      = (float*)ws;   ws += hElems * sizeof(float);
    float* h2      = (float*)ws;   ws += hElems * sizeof(float);
    float* h3      = (float*)ws;   ws += hElems * sizeof(float);
    int*   counts  = (int*)ws;     ws += NNODES * sizeof(int);
    int*   startp  = (int*)ws;     ws += NNODES * sizeof(int);
    int*   slot    = (int*)ws;     ws += NNZV * sizeof(int);
    int*   partials= (int*)ws;     ws += 128 * sizeof(int);
    int2*  desc    = (int2*)ws;    ws += NNODES * sizeof(int2);
    int2*  edges   = (int2*)ws;    ws += NNZV * sizeof(int2);

    hipMemsetAsync(counts, 0, NNODES * sizeof(int), stream);

    // ---- CSR build
    int eblk256 = (NNZV + 255) / 256;
    count_rows     <<<eblk256, 256, 0, stream>>>(arow, counts, slot);
    scan_block     <<<SCAN_GRID, SCAN_BLK, 0, stream>>>(counts, startp, partials);
    scan_partials  <<<1, 128, 0, stream>>>(partials);
    add_offsets_desc<<<SCAN_GRID, SCAN_BLK, 0, stream>>>(startp, partials, counts, desc);
    scatter_edges  <<<eblk256, 256, 0, stream>>>(arow, acol, aval, startp, slot, edges);

    // ---- 3 pull-SpMM layers
    int rblocks = (NNODES + 7) / 8;
    spmm_pull_first<<<rblocks, 256, 0, stream>>>(desc, edges, ue, ie, h1);
    spmm_pull      <<<rblocks, 256, 0, stream>>>(desc, edges, h1, h2);
    spmm_pull      <<<rblocks, 256, 0, stream>>>(desc, edges, h2, h3);

    // ---- outputs
    float* out = (float*)d_out;
    float* i_g = out + (size_t)3 * BATCHN * EMB;

    int g3blocks = (3 * BATCHN + 7) / 8;
    finalize_gather3<<<g3blocks, 256, 0, stream>>>(users, pos, neg, ue, ie, h1, h2, h3, out);

    int iblocks = (NITEMS * EMB / 4 + 255) / 256;
    finalize_items<<<iblocks, 256, 0, stream>>>(ie, h1, h2, h3, i_g);
}